// Round 1
// baseline (106.551 us; speedup 1.0000x reference)
//
#include <hip/hip_runtime.h>

// B=2, HEADS=8, T=8, QH=QW=16, D=64; rows = B*H*T*QH*QW = 32768, K = 2048.
// out[row, k] = scores[row, k] + dotH(qh,kh) + dotW(qw,kw) + dotT(t,kt)
// where k = kt*256 + kh*16 + kw, row = (b*H+n)*2048 + t*256 + qh*16 + qw.

__global__ __launch_bounds__(256) void relpos_fused_kernel(
    const float* __restrict__ query,   // [32768, 64]
    const float* __restrict__ scores,  // [32768, 2048]
    const float* __restrict__ hemb,    // [31, 64]
    const float* __restrict__ wemb,    // [31, 64]
    const float* __restrict__ temb,    // [15, 64]
    float* __restrict__ out)           // [32768, 2048]
{
    __shared__ float q_lds[64];
    __shared__ float relH[16];
    __shared__ float relW[16];   // read as float4[4]
    __shared__ float relT[8];
    __shared__ float relTH[128]; // relT[kt] + relH[kh], index kt*16+kh

    const int bid = blockIdx.x;        // query-row id, [0, 32768)
    const int tid = threadIdx.x;       // [0, 256)
    const int row = bid & 2047;        // within (b,n)
    const int t   = row >> 8;
    const int qh  = (row >> 4) & 15;
    const int qw  = row & 15;

    // Stage the 64-float query row into LDS (16 lanes x float4).
    if (tid < 16) {
        ((float4*)q_lds)[tid] =
            ((const float4*)(query + (size_t)bid * 64))[tid];
    }
    __syncthreads();

    // 40 dot products: threads 0..15 -> kh, 16..31 -> kw, 32..39 -> kt.
    if (tid < 40) {
        const float* emb;
        int eidx;
        if (tid < 16)      { emb = hemb; eidx = qh - tid + 15; }
        else if (tid < 32) { emb = wemb; eidx = qw - (tid - 16) + 15; }
        else               { emb = temb; eidx = t  - (tid - 32) + 7; }
        const float4* e4 = (const float4*)(emb + eidx * 64);
        const float4* q4p = (const float4*)q_lds;
        float acc = 0.f;
        #pragma unroll
        for (int k = 0; k < 16; ++k) {
            float4 q4 = q4p[k];
            float4 e  = e4[k];
            acc += q4.x * e.x + q4.y * e.y + q4.z * e.z + q4.w * e.w;
        }
        if (tid < 16)      relH[tid] = acc;
        else if (tid < 32) relW[tid - 16] = acc;
        else               relT[tid - 32] = acc;
    }
    __syncthreads();

    if (tid < 128) {
        relTH[tid] = relT[tid >> 4] + relH[tid & 15];
    }
    __syncthreads();

    // Stream the 2048-element row: 512 float4s, 256 threads, 2 iterations.
    const size_t base4 = (size_t)bid * 512;           // float4 index base
    const float4* s4p = (const float4*)scores + base4;
    float4* o4p = (float4*)out + base4;
    const float4* w4p = (const float4*)relW;

    #pragma unroll
    for (int it = 0; it < 2; ++it) {
        const int j4 = tid + it * 256;   // float4 index in row, [0,512)
        float4 s = s4p[j4];
        const float a  = relTH[j4 >> 2]; // (kt*16+kh) == (j4*4)>>4
        const float4 w = w4p[j4 & 3];    // kw block
        float4 o;
        o.x = s.x + a + w.x;
        o.y = s.y + a + w.y;
        o.z = s.z + a + w.z;
        o.w = s.w + a + w.w;
        o4p[j4] = o;
    }
}

extern "C" void kernel_launch(void* const* d_in, const int* in_sizes, int n_in,
                              void* d_out, int out_size, void* d_ws, size_t ws_size,
                              hipStream_t stream) {
    const float* query  = (const float*)d_in[0];
    const float* scores = (const float*)d_in[1];
    const float* hemb   = (const float*)d_in[2];
    const float* wemb   = (const float*)d_in[3];
    const float* temb   = (const float*)d_in[4];
    float* out = (float*)d_out;

    // 32768 query rows, one block each.
    relpos_fused_kernel<<<32768, 256, 0, stream>>>(
        query, scores, hemb, wemb, temb, out);
}

// Round 3
// 104.710 us; speedup vs baseline: 1.0176x; 1.0176x over previous
//
#include <hip/hip_runtime.h>

// B=2, HEADS=8, T=8, QH=QW=16, D=64; rows = 32768, K = 2048.
// out[row, k] = scores[row, k] + dotH(qh,kh) + dotW(qw,kw) + dotT(t,kt)
// k = kt*256 + kh*16 + kw; row = (b*H+n)*2048 + t*256 + qh*16 + qw.
//
// v3: v2 with clang ext_vector float4 for nontemporal load/store
// (HIP_vector_type is a struct and rejected by the builtin).

#define ROWS 4

typedef float v4f __attribute__((ext_vector_type(4)));

__global__ __launch_bounds__(256) void relpos_fused_v3(
    const float* __restrict__ query,   // [32768, 64]
    const float* __restrict__ scores,  // [32768, 2048]
    const float* __restrict__ hemb,    // [31, 64]
    const float* __restrict__ wemb,    // [31, 64]
    const float* __restrict__ temb,    // [15, 64]
    float* __restrict__ out)           // [32768, 2048]
{
    __shared__ float biasH[ROWS][16];
    __shared__ float biasW[ROWS][16];  // read as v4f[4]
    __shared__ float biasT[ROWS][8];

    const int bid  = blockIdx.x;        // [0, 8192)
    const int tid  = threadIdx.x;       // [0, 256)
    const int wv   = tid >> 6;          // wave id == local row [0,4)
    const int lane = tid & 63;

    const int r0   = bid * ROWS;
    const int row  = (r0 + wv) & 2047;  // within (b,n)
    const int t    = row >> 8;
    const int qh   = (row >> 4) & 15;
    const int qw   = row & 15;

    // --- Prelude: 40 dots per row, one thread each, straight from global ---
    if (lane < 40) {
        const float* emb;
        int eidx;
        if (lane < 16)      { emb = hemb; eidx = qh - lane + 15; }
        else if (lane < 32) { emb = wemb; eidx = qw - (lane - 16) + 15; }
        else                { emb = temb; eidx = t  - (lane - 32) + 7; }
        const v4f* e4 = (const v4f*)(emb + eidx * 64);
        const v4f* q4 = (const v4f*)(query + (size_t)(r0 + wv) * 64);
        v4f a4 = (v4f)(0.f);
        #pragma unroll
        for (int k = 0; k < 16; ++k) {
            a4 += q4[k] * e4[k];
        }
        const float acc = (a4.x + a4.y) + (a4.z + a4.w);
        if (lane < 16)      biasH[wv][lane] = acc;
        else if (lane < 32) biasW[wv][lane - 16] = acc;
        else                biasT[wv][lane - 32] = acc;
    }
    __syncthreads();

    // --- Stream: block covers 4 rows = 2048 float4s, 8 iters x 256 threads ---
    const size_t base4 = (size_t)bid * (ROWS * 512);
    const v4f* s4p = (const v4f*)scores + base4;
    v4f* o4p = (v4f*)out + base4;

    #pragma unroll
    for (int i = 0; i < 2 * ROWS; ++i) {
        const int idx = tid + i * 256;   // [0, 2048)
        const int rl  = idx >> 9;        // local row
        const int j   = idx & 511;       // float4 index within row
        v4f s = __builtin_nontemporal_load(&s4p[idx]);
        const float a = biasT[rl][j >> 6] + biasH[rl][(j >> 2) & 15];
        const v4f w = ((const v4f*)biasW[rl])[j & 3];
        v4f o = s + a + w;
        __builtin_nontemporal_store(o, &o4p[idx]);
    }
}

extern "C" void kernel_launch(void* const* d_in, const int* in_sizes, int n_in,
                              void* d_out, int out_size, void* d_ws, size_t ws_size,
                              hipStream_t stream) {
    const float* query  = (const float*)d_in[0];
    const float* scores = (const float*)d_in[1];
    const float* hemb   = (const float*)d_in[2];
    const float* wemb   = (const float*)d_in[3];
    const float* temb   = (const float*)d_in[4];
    float* out = (float*)d_out;

    relpos_fused_v3<<<32768 / ROWS, 256, 0, stream>>>(
        query, scores, hemb, wemb, temb, out);
}